// Round 1
// baseline (468.455 us; speedup 1.0000x reference)
//
#include <hip/hip_runtime.h>

#define NEG_SLOPE 0.01f

// ---------------- degree / CSR build ----------------

__global__ void init_counts(int* counts, int n) {
    int i = blockIdx.x * blockDim.x + threadIdx.x;
    if (i < n) counts[i] = 0;
}

__global__ void count_edges(const int* __restrict__ dst, int* counts, int E) {
    int e = blockIdx.x * blockDim.x + threadIdx.x;
    if (e < E) atomicAdd(&counts[dst[e]], 1);
}

// per-1024-block exclusive scan; blockSums[b] = block total
__global__ void scan_blocks(const int* __restrict__ counts, int* row_ptr,
                            int* blockSums, int n) {
    int tid = threadIdx.x;
    int gid = blockIdx.x * 1024 + tid;
    int v = (gid < n) ? counts[gid] : 0;
    int lane = tid & 63, wave = tid >> 6;
    __shared__ int waveSums[16];
    __shared__ int waveOff[16];
    int s = v;
    #pragma unroll
    for (int off = 1; off < 64; off <<= 1) {
        int t = __shfl_up(s, off);
        if (lane >= off) s += t;
    }
    if (lane == 63) waveSums[wave] = s;
    __syncthreads();
    if (tid == 0) {
        int acc = 0;
        for (int w = 0; w < 16; w++) { waveOff[w] = acc; acc += waveSums[w]; }
        blockSums[blockIdx.x] = acc;
    }
    __syncthreads();
    if (gid < n) row_ptr[gid] = s - v + waveOff[wave];
}

__global__ void scan_sums(int* blockSums, int nb) {
    if (threadIdx.x == 0 && blockIdx.x == 0) {
        int acc = 0;
        for (int b = 0; b < nb; b++) { int t = blockSums[b]; blockSums[b] = acc; acc += t; }
    }
}

// row_ptr += blockSums[bid]; dis = rsqrt(1+count); cursor (aliases counts) = row_ptr
__global__ void finalize_scan(int* row_ptr, const int* __restrict__ blockSums,
                              int* cursor_counts, float* dis, int n) {
    int gid = blockIdx.x * 1024 + threadIdx.x;
    if (gid < n) {
        int c = cursor_counts[gid];                    // original count (pre-overwrite)
        dis[gid] = rsqrtf(1.0f + (float)c);            // self-loop folded into degree
        int rp = row_ptr[gid] + blockSums[blockIdx.x];
        row_ptr[gid] = rp;
        cursor_counts[gid] = rp;                       // becomes allocation cursor
    }
}

__global__ void fill_csr(const int* __restrict__ src, const int* __restrict__ dst,
                         int* cursor, const float* __restrict__ dis,
                         int* csr_src, float* csr_norm, int E) {
    int e = blockIdx.x * blockDim.x + threadIdx.x;
    if (e < E) {
        int s = src[e], d = dst[e];
        int pos = atomicAdd(&cursor[d], 1);
        csr_src[pos] = s;
        csr_norm[pos] = dis[s] * dis[d];
    }
}

// ---------------- fp32 tiled GEMM: C[M,128] = A[M,K] @ B[K,128] ----------------
// BM=64, BN=128, BK=16, 256 threads, 4x8 per-thread tile.

__launch_bounds__(256)
__global__ void gemm_tile(const float* __restrict__ A, const float* __restrict__ B,
                          float* __restrict__ C, int M, int K) {
    __shared__ float AsT[16][64];    // [k][m] so compute reads are float4 along m
    __shared__ float Bs[16][128];
    int tid = threadIdx.x;
    int tx = tid & 15;               // col group: cols tx*8..tx*8+7
    int ty = tid >> 4;               // row group: rows ty*4..ty*4+3
    int row0 = blockIdx.x * 64;

    float acc[4][8];
    #pragma unroll
    for (int i = 0; i < 4; i++)
        #pragma unroll
        for (int j = 0; j < 8; j++) acc[i][j] = 0.f;

    int aIdx = tid * 4;
    int am = aIdx >> 4;              // row within tile
    int ak = aIdx & 15;              // k within tile (multiple of 4)
    int arow = row0 + am;
    int arowc = (arow < M) ? arow : (M - 1);   // clamp (stores are guarded)
    const float* aBase = A + (size_t)arowc * K + ak;
    const float* bBase = B + (size_t)ty * 128 + tx * 8;

    for (int kt = 0; kt < K; kt += 16) {
        float4 av = *(const float4*)(aBase + kt);
        AsT[ak + 0][am] = av.x;
        AsT[ak + 1][am] = av.y;
        AsT[ak + 2][am] = av.z;
        AsT[ak + 3][am] = av.w;
        float4 b0 = *(const float4*)(bBase + (size_t)kt * 128);
        float4 b1 = *(const float4*)(bBase + (size_t)kt * 128 + 4);
        *(float4*)&Bs[ty][tx * 8]     = b0;
        *(float4*)&Bs[ty][tx * 8 + 4] = b1;
        __syncthreads();
        #pragma unroll
        for (int kk = 0; kk < 16; kk++) {
            float4 a4  = *(const float4*)&AsT[kk][ty * 4];
            float4 bv0 = *(const float4*)&Bs[kk][tx * 8];
            float4 bv1 = *(const float4*)&Bs[kk][tx * 8 + 4];
            float a[4] = {a4.x, a4.y, a4.z, a4.w};
            float b[8] = {bv0.x, bv0.y, bv0.z, bv0.w, bv1.x, bv1.y, bv1.z, bv1.w};
            #pragma unroll
            for (int i = 0; i < 4; i++)
                #pragma unroll
                for (int j = 0; j < 8; j++)
                    acc[i][j] = fmaf(a[i], b[j], acc[i][j]);
        }
        __syncthreads();
    }
    #pragma unroll
    for (int i = 0; i < 4; i++) {
        int r = row0 + ty * 4 + i;
        if (r < M) {
            float4 o0 = make_float4(acc[i][0], acc[i][1], acc[i][2], acc[i][3]);
            float4 o1 = make_float4(acc[i][4], acc[i][5], acc[i][6], acc[i][7]);
            *(float4*)(C + (size_t)r * 128 + tx * 8)     = o0;
            *(float4*)(C + (size_t)r * 128 + tx * 8 + 4) = o1;
        }
    }
}

__global__ void pack_w(const float* __restrict__ Wmu, const float* __restrict__ Wlv,
                       float* __restrict__ Wcat) {
    int i = blockIdx.x * blockDim.x + threadIdx.x;
    if (i < 128 * 128) {
        int k = i >> 7, c = i & 127;
        Wcat[i] = (c < 64) ? Wmu[k * 64 + c] : Wlv[k * 64 + (c - 64)];
    }
}

// ---------------- aggregation: one block (128 thr) per node ----------------

__launch_bounds__(128)
__global__ void agg_layer1(const float* __restrict__ z, const int* __restrict__ row_ptr,
                           const int* __restrict__ row_end, const int* __restrict__ csr_src,
                           const float* __restrict__ csr_norm, const float* __restrict__ dis,
                           const float* __restrict__ b1, float* __restrict__ h) {
    int node = blockIdx.x;
    int f = threadIdx.x;
    int start = row_ptr[node], end = row_end[node];
    float acc = 0.f;
    for (int e = start; e < end; e++) {
        int s = csr_src[e];
        float nw = csr_norm[e];
        acc = fmaf(nw, z[(size_t)s * 128 + f], acc);
    }
    float di = dis[node];
    acc = fmaf(di * di, z[(size_t)node * 128 + f], acc);   // self loop
    acc += b1[f];
    h[(size_t)node * 128 + f] = (acc > 0.f) ? acc : NEG_SLOPE * acc;
}

__launch_bounds__(128)
__global__ void agg_layer2(const float* __restrict__ z, const int* __restrict__ row_ptr,
                           const int* __restrict__ row_end, const int* __restrict__ csr_src,
                           const float* __restrict__ csr_norm, const float* __restrict__ dis,
                           const float* __restrict__ b_mu, const float* __restrict__ b_lv,
                           float* __restrict__ out, int N) {
    int node = blockIdx.x;
    int f = threadIdx.x;
    int start = row_ptr[node], end = row_end[node];
    float acc = 0.f;
    for (int e = start; e < end; e++) {
        int s = csr_src[e];
        float nw = csr_norm[e];
        acc = fmaf(nw, z[(size_t)s * 128 + f], acc);
    }
    float di = dis[node];
    acc = fmaf(di * di, z[(size_t)node * 128 + f], acc);
    if (f < 64)
        out[(size_t)node * 64 + f] = acc + b_mu[f];                        // mu
    else
        out[(size_t)N * 64 + (size_t)node * 64 + (f - 64)] = acc + b_lv[f - 64];  // logvar
}

// ---------------- launcher ----------------

extern "C" void kernel_launch(void* const* d_in, const int* in_sizes, int n_in,
                              void* d_out, int out_size, void* d_ws, size_t ws_size,
                              hipStream_t stream) {
    const float* x   = (const float*)d_in[0];
    const int*   ei  = (const int*)d_in[1];    // [2,E] int32: src then dst
    const float* W1  = (const float*)d_in[2];
    const float* b1  = (const float*)d_in[3];
    const float* Wmu = (const float*)d_in[4];
    const float* bmu = (const float*)d_in[5];
    const float* Wlv = (const float*)d_in[6];
    const float* blv = (const float*)d_in[7];
    float* out = (float*)d_out;

    const int F_IN = 256;
    int N = in_sizes[0] / F_IN;   // 50000
    int E = in_sizes[1] / 2;      // 800000
    const int* e_src = ei;
    const int* e_dst = ei + E;

    char* ws = (char*)d_ws;
    size_t off = 0;
    auto carve = [&](size_t bytes) -> void* {
        void* p = ws + off;
        off += (bytes + 255) & ~(size_t)255;
        return p;
    };
    int*   counts   = (int*)  carve((size_t)N * 4);        // later: cursor / row_end
    int*   row_ptr  = (int*)  carve((size_t)N * 4);
    int*   blockSums= (int*)  carve(64 * 4);
    float* dis      = (float*)carve((size_t)N * 4);
    int*   csr_src  = (int*)  carve((size_t)E * 4);
    float* csr_norm = (float*)carve((size_t)E * 4);
    float* bufA     = (float*)carve((size_t)N * 128 * 4);  // Z1, then Z2
    float* bufB     = (float*)carve((size_t)N * 128 * 4);  // h
    float* Wcat     = (float*)carve(128 * 128 * 4);

    int nb = (N + 1023) / 1024;

    hipLaunchKernelGGL(init_counts, dim3((N + 255) / 256), dim3(256), 0, stream, counts, N);
    hipLaunchKernelGGL(count_edges, dim3((E + 255) / 256), dim3(256), 0, stream, e_dst, counts, E);
    hipLaunchKernelGGL(scan_blocks, dim3(nb), dim3(1024), 0, stream, counts, row_ptr, blockSums, N);
    hipLaunchKernelGGL(scan_sums, dim3(1), dim3(64), 0, stream, blockSums, nb);
    hipLaunchKernelGGL(finalize_scan, dim3(nb), dim3(1024), 0, stream, row_ptr, blockSums, counts, dis, N);
    hipLaunchKernelGGL(fill_csr, dim3((E + 255) / 256), dim3(256), 0, stream,
                       e_src, e_dst, counts, dis, csr_src, csr_norm, E);
    // layer 1: Z1 = x @ W1 ; h = leaky(Agg(Z1) + b1)
    hipLaunchKernelGGL(gemm_tile, dim3((N + 63) / 64), dim3(256), 0, stream, x, W1, bufA, N, F_IN);
    hipLaunchKernelGGL(agg_layer1, dim3(N), dim3(128), 0, stream,
                       bufA, row_ptr, counts, csr_src, csr_norm, dis, b1, bufB);
    // layer 2 (mu & logvar share the aggregation): Z2 = h @ [Wmu|Wlv]
    hipLaunchKernelGGL(pack_w, dim3(64), dim3(256), 0, stream, Wmu, Wlv, Wcat);
    hipLaunchKernelGGL(gemm_tile, dim3((N + 63) / 64), dim3(256), 0, stream, bufB, Wcat, bufA, N, 128);
    hipLaunchKernelGGL(agg_layer2, dim3(N), dim3(128), 0, stream,
                       bufA, row_ptr, counts, csr_src, csr_norm, dis, bmu, blv, out, N);
}

// Round 2
// 399.904 us; speedup vs baseline: 1.1714x; 1.1714x over previous
//
#include <hip/hip_runtime.h>

#define NEG_SLOPE 0.01f

// ---------------- degree / CSR build ----------------

__global__ void init_counts(int* counts, int n) {
    int i = blockIdx.x * blockDim.x + threadIdx.x;
    if (i < n) counts[i] = 0;
}

__global__ void count_edges(const int* __restrict__ dst, int* counts, int E) {
    int e = blockIdx.x * blockDim.x + threadIdx.x;
    if (e < E) atomicAdd(&counts[dst[e]], 1);
}

// per-1024-block exclusive scan; blockSums[b] = block total
__global__ void scan_blocks(const int* __restrict__ counts, int* row_ptr,
                            int* blockSums, int n) {
    int tid = threadIdx.x;
    int gid = blockIdx.x * 1024 + tid;
    int v = (gid < n) ? counts[gid] : 0;
    int lane = tid & 63, wave = tid >> 6;
    __shared__ int waveSums[16];
    __shared__ int waveOff[16];
    int s = v;
    #pragma unroll
    for (int off = 1; off < 64; off <<= 1) {
        int t = __shfl_up(s, off);
        if (lane >= off) s += t;
    }
    if (lane == 63) waveSums[wave] = s;
    __syncthreads();
    if (tid == 0) {
        int acc = 0;
        for (int w = 0; w < 16; w++) { waveOff[w] = acc; acc += waveSums[w]; }
        blockSums[blockIdx.x] = acc;
    }
    __syncthreads();
    if (gid < n) row_ptr[gid] = s - v + waveOff[wave];
}

__global__ void scan_sums(int* blockSums, int nb) {
    if (threadIdx.x == 0 && blockIdx.x == 0) {
        int acc = 0;
        for (int b = 0; b < nb; b++) { int t = blockSums[b]; blockSums[b] = acc; acc += t; }
    }
}

// row_ptr += blockSums[bid]; dis = rsqrt(1+count); cursor (aliases counts) = row_ptr
__global__ void finalize_scan(int* row_ptr, const int* __restrict__ blockSums,
                              int* cursor_counts, float* dis, int n) {
    int gid = blockIdx.x * 1024 + threadIdx.x;
    if (gid < n) {
        int c = cursor_counts[gid];                    // original count (pre-overwrite)
        dis[gid] = rsqrtf(1.0f + (float)c);            // self-loop folded into degree
        int rp = row_ptr[gid] + blockSums[blockIdx.x];
        row_ptr[gid] = rp;
        cursor_counts[gid] = rp;                       // becomes allocation cursor
    }
}

// norms are folded into row pre-scaling now -> CSR stores src only
__global__ void fill_csr(const int* __restrict__ src, const int* __restrict__ dst,
                         int* cursor, int* csr_src, int E) {
    int e = blockIdx.x * blockDim.x + threadIdx.x;
    if (e < E) {
        int s = src[e], d = dst[e];
        int pos = atomicAdd(&cursor[d], 1);
        csr_src[pos] = s;
    }
}

// ---------------- fp32 tiled GEMM: C[M,128] = A[M,K] @ B[K,128] ----------------
// BM=64, BN=128, BK=16, 256 threads, 4x8 per-thread tile.
// Optional epilogue: scale row r by dis[r] (folds GCN norm into the feature rows).

__launch_bounds__(256)
__global__ void gemm_tile(const float* __restrict__ A, const float* __restrict__ B,
                          float* __restrict__ C, int M, int K,
                          const float* __restrict__ dis) {
    __shared__ float AsT[16][64];    // [k][m] so compute reads are float4 along m
    __shared__ float Bs[16][128];
    int tid = threadIdx.x;
    int tx = tid & 15;               // col group: cols tx*8..tx*8+7
    int ty = tid >> 4;               // row group: rows ty*4..ty*4+3
    int row0 = blockIdx.x * 64;

    float acc[4][8];
    #pragma unroll
    for (int i = 0; i < 4; i++)
        #pragma unroll
        for (int j = 0; j < 8; j++) acc[i][j] = 0.f;

    int aIdx = tid * 4;
    int am = aIdx >> 4;              // row within tile
    int ak = aIdx & 15;              // k within tile (multiple of 4)
    int arow = row0 + am;
    int arowc = (arow < M) ? arow : (M - 1);   // clamp (stores are guarded)
    const float* aBase = A + (size_t)arowc * K + ak;
    const float* bBase = B + (size_t)ty * 128 + tx * 8;

    for (int kt = 0; kt < K; kt += 16) {
        float4 av = *(const float4*)(aBase + kt);
        AsT[ak + 0][am] = av.x;
        AsT[ak + 1][am] = av.y;
        AsT[ak + 2][am] = av.z;
        AsT[ak + 3][am] = av.w;
        float4 b0 = *(const float4*)(bBase + (size_t)kt * 128);
        float4 b1 = *(const float4*)(bBase + (size_t)kt * 128 + 4);
        *(float4*)&Bs[ty][tx * 8]     = b0;
        *(float4*)&Bs[ty][tx * 8 + 4] = b1;
        __syncthreads();
        #pragma unroll
        for (int kk = 0; kk < 16; kk++) {
            float4 a4  = *(const float4*)&AsT[kk][ty * 4];
            float4 bv0 = *(const float4*)&Bs[kk][tx * 8];
            float4 bv1 = *(const float4*)&Bs[kk][tx * 8 + 4];
            float a[4] = {a4.x, a4.y, a4.z, a4.w};
            float b[8] = {bv0.x, bv0.y, bv0.z, bv0.w, bv1.x, bv1.y, bv1.z, bv1.w};
            #pragma unroll
            for (int i = 0; i < 4; i++)
                #pragma unroll
                for (int j = 0; j < 8; j++)
                    acc[i][j] = fmaf(a[i], b[j], acc[i][j]);
        }
        __syncthreads();
    }
    #pragma unroll
    for (int i = 0; i < 4; i++) {
        int r = row0 + ty * 4 + i;
        if (r < M) {
            float s = dis ? dis[r] : 1.f;
            float4 o0 = make_float4(s * acc[i][0], s * acc[i][1], s * acc[i][2], s * acc[i][3]);
            float4 o1 = make_float4(s * acc[i][4], s * acc[i][5], s * acc[i][6], s * acc[i][7]);
            *(float4*)(C + (size_t)r * 128 + tx * 8)     = o0;
            *(float4*)(C + (size_t)r * 128 + tx * 8 + 4) = o1;
        }
    }
}

__global__ void pack_w(const float* __restrict__ Wmu, const float* __restrict__ Wlv,
                       float* __restrict__ Wcat) {
    int i = blockIdx.x * blockDim.x + threadIdx.x;
    if (i < 128 * 128) {
        int k = i >> 7, c = i & 127;
        Wcat[i] = (c < 64) ? Wmu[k * 64 + c] : Wlv[k * 64 + (c - 64)];
    }
}

// ---------------- aggregation: one WAVE per node, float4 row gathers ----------------
// zp holds pre-scaled rows z'[i] = dis[i] * (transform(x))[i].
// out_node = dis[d] * ( sum_{s in N(d)} z'[s] + z'[d] ) + bias
// Half-wave 0 (lanes 0..31) takes even CSR slots, half-wave 1 odd slots;
// each half gathers a full 512B row per float4 instruction; unroll x2 ->
// 4 independent row-gathers in flight per wave.

#define AGG_BODY                                                            \
    int wave = threadIdx.x >> 6;                                            \
    int node = blockIdx.x * 4 + wave;                                       \
    if (node >= N) return;                                                  \
    int lane = threadIdx.x & 63;                                            \
    int half = lane >> 5;                                                   \
    int fl = lane & 31;                                                     \
    int fo = fl * 4;                                                        \
    const float* zb = zp + fo;                                              \
    int start = row_ptr[node], end = row_end[node];                         \
    float4 a0 = make_float4(0.f, 0.f, 0.f, 0.f);                            \
    float4 a1 = a0;                                                         \
    int e = start + half;                                                   \
    for (; e + 2 < end; e += 4) {                                           \
        int s0 = csr_src[e], s1 = csr_src[e + 2];                           \
        float4 z0 = *(const float4*)(zb + (size_t)s0 * 128);                \
        float4 z1 = *(const float4*)(zb + (size_t)s1 * 128);                \
        a0.x += z0.x; a0.y += z0.y; a0.z += z0.z; a0.w += z0.w;             \
        a1.x += z1.x; a1.y += z1.y; a1.z += z1.z; a1.w += z1.w;             \
    }                                                                       \
    if (e < end) {                                                          \
        int s0 = csr_src[e];                                                \
        float4 z0 = *(const float4*)(zb + (size_t)s0 * 128);                \
        a0.x += z0.x; a0.y += z0.y; a0.z += z0.z; a0.w += z0.w;             \
    }                                                                       \
    if (half == 0) {  /* self loop, added exactly once */                   \
        float4 zs = *(const float4*)(zb + (size_t)node * 128);              \
        a0.x += zs.x; a0.y += zs.y; a0.z += zs.z; a0.w += zs.w;             \
    }                                                                       \
    a0.x += a1.x; a0.y += a1.y; a0.z += a1.z; a0.w += a1.w;                 \
    a0.x += __shfl_xor(a0.x, 32);                                           \
    a0.y += __shfl_xor(a0.y, 32);                                           \
    a0.z += __shfl_xor(a0.z, 32);                                           \
    a0.w += __shfl_xor(a0.w, 32);

__launch_bounds__(256)
__global__ void agg_layer1(const float* __restrict__ zp, const int* __restrict__ row_ptr,
                           const int* __restrict__ row_end, const int* __restrict__ csr_src,
                           const float* __restrict__ dis, const float* __restrict__ b1,
                           float* __restrict__ h, int N) {
    AGG_BODY
    if (half == 0) {
        float d = dis[node];
        float4 bv = *(const float4*)(b1 + fo);
        float4 o;
        o.x = fmaf(d, a0.x, bv.x);
        o.y = fmaf(d, a0.y, bv.y);
        o.z = fmaf(d, a0.z, bv.z);
        o.w = fmaf(d, a0.w, bv.w);
        o.x = (o.x > 0.f) ? o.x : NEG_SLOPE * o.x;
        o.y = (o.y > 0.f) ? o.y : NEG_SLOPE * o.y;
        o.z = (o.z > 0.f) ? o.z : NEG_SLOPE * o.z;
        o.w = (o.w > 0.f) ? o.w : NEG_SLOPE * o.w;
        *(float4*)(h + (size_t)node * 128 + fo) = o;
    }
}

__launch_bounds__(256)
__global__ void agg_layer2(const float* __restrict__ zp, const int* __restrict__ row_ptr,
                           const int* __restrict__ row_end, const int* __restrict__ csr_src,
                           const float* __restrict__ dis, const float* __restrict__ b_mu,
                           const float* __restrict__ b_lv, float* __restrict__ out, int N) {
    AGG_BODY
    if (half == 0) {
        float d = dis[node];
        if (fl < 16) {                       // mu: features fo..fo+3
            float4 bv = *(const float4*)(b_mu + fo);
            float4 o;
            o.x = fmaf(d, a0.x, bv.x);
            o.y = fmaf(d, a0.y, bv.y);
            o.z = fmaf(d, a0.z, bv.z);
            o.w = fmaf(d, a0.w, bv.w);
            *(float4*)(out + (size_t)node * 64 + fo) = o;
        } else {                             // logvar: features fo-64..fo-61
            float4 bv = *(const float4*)(b_lv + (fo - 64));
            float4 o;
            o.x = fmaf(d, a0.x, bv.x);
            o.y = fmaf(d, a0.y, bv.y);
            o.z = fmaf(d, a0.z, bv.z);
            o.w = fmaf(d, a0.w, bv.w);
            *(float4*)(out + (size_t)N * 64 + (size_t)node * 64 + (fo - 64)) = o;
        }
    }
}

// ---------------- launcher ----------------

extern "C" void kernel_launch(void* const* d_in, const int* in_sizes, int n_in,
                              void* d_out, int out_size, void* d_ws, size_t ws_size,
                              hipStream_t stream) {
    const float* x   = (const float*)d_in[0];
    const int*   ei  = (const int*)d_in[1];    // [2,E] int32: src then dst
    const float* W1  = (const float*)d_in[2];
    const float* b1  = (const float*)d_in[3];
    const float* Wmu = (const float*)d_in[4];
    const float* bmu = (const float*)d_in[5];
    const float* Wlv = (const float*)d_in[6];
    const float* blv = (const float*)d_in[7];
    float* out = (float*)d_out;

    const int F_IN = 256;
    int N = in_sizes[0] / F_IN;   // 50000
    int E = in_sizes[1] / 2;      // 800000
    const int* e_src = ei;
    const int* e_dst = ei + E;

    char* ws = (char*)d_ws;
    size_t off = 0;
    auto carve = [&](size_t bytes) -> void* {
        void* p = ws + off;
        off += (bytes + 255) & ~(size_t)255;
        return p;
    };
    int*   counts   = (int*)  carve((size_t)N * 4);        // later: cursor / row_end
    int*   row_ptr  = (int*)  carve((size_t)N * 4);
    int*   blockSums= (int*)  carve(64 * 4);
    float* dis      = (float*)carve((size_t)N * 4);
    int*   csr_src  = (int*)  carve((size_t)E * 4);
    float* bufA     = (float*)carve((size_t)N * 128 * 4);  // Z1', then Z2'
    float* bufB     = (float*)carve((size_t)N * 128 * 4);  // h
    float* Wcat     = (float*)carve(128 * 128 * 4);

    int nb = (N + 1023) / 1024;

    hipLaunchKernelGGL(init_counts, dim3((N + 255) / 256), dim3(256), 0, stream, counts, N);
    hipLaunchKernelGGL(count_edges, dim3((E + 255) / 256), dim3(256), 0, stream, e_dst, counts, E);
    hipLaunchKernelGGL(scan_blocks, dim3(nb), dim3(1024), 0, stream, counts, row_ptr, blockSums, N);
    hipLaunchKernelGGL(scan_sums, dim3(1), dim3(64), 0, stream, blockSums, nb);
    hipLaunchKernelGGL(finalize_scan, dim3(nb), dim3(1024), 0, stream, row_ptr, blockSums, counts, dis, N);
    hipLaunchKernelGGL(fill_csr, dim3((E + 255) / 256), dim3(256), 0, stream,
                       e_src, e_dst, counts, csr_src, E);
    // layer 1: Z1' = dis .* (x @ W1) ; h = leaky(dis .* Agg(Z1') + b1)
    hipLaunchKernelGGL(gemm_tile, dim3((N + 63) / 64), dim3(256), 0, stream, x, W1, bufA, N, F_IN, dis);
    hipLaunchKernelGGL(agg_layer1, dim3((N + 3) / 4), dim3(256), 0, stream,
                       bufA, row_ptr, counts, csr_src, dis, b1, bufB, N);
    // layer 2 (mu & logvar share the aggregation): Z2' = dis .* (h @ [Wmu|Wlv])
    hipLaunchKernelGGL(pack_w, dim3(64), dim3(256), 0, stream, Wmu, Wlv, Wcat);
    hipLaunchKernelGGL(gemm_tile, dim3((N + 63) / 64), dim3(256), 0, stream, bufB, Wcat, bufA, N, 128, dis);
    hipLaunchKernelGGL(agg_layer2, dim3((N + 3) / 4), dim3(256), 0, stream,
                       bufA, row_ptr, counts, csr_src, dis, bmu, blv, out, N);
}

// Round 3
// 372.578 us; speedup vs baseline: 1.2573x; 1.0733x over previous
//
#include <hip/hip_runtime.h>

#define NEG_SLOPE 0.01f

typedef __attribute__((ext_vector_type(8))) short bf16x8;
typedef __attribute__((ext_vector_type(4))) float floatx4;

__device__ __forceinline__ short f2bf(float f) {
    union { float f; unsigned u; } v; v.f = f;
    unsigned u = v.u;
    u += 0x7FFF + ((u >> 16) & 1);          // round-to-nearest-even
    return (short)(u >> 16);
}

// ---------------- degree / CSR build ----------------

__global__ void init_counts(int* counts, int n) {
    int i = blockIdx.x * blockDim.x + threadIdx.x;
    if (i < n) counts[i] = 0;
}

__global__ void count_edges(const int* __restrict__ dst, int* counts, int E) {
    int e = blockIdx.x * blockDim.x + threadIdx.x;
    if (e < E) atomicAdd(&counts[dst[e]], 1);
}

// per-1024-block exclusive scan; blockSums[b] = block total
__global__ void scan_blocks(const int* __restrict__ counts, int* row_ptr,
                            int* blockSums, int n) {
    int tid = threadIdx.x;
    int gid = blockIdx.x * 1024 + tid;
    int v = (gid < n) ? counts[gid] : 0;
    int lane = tid & 63, wave = tid >> 6;
    __shared__ int waveSums[16];
    __shared__ int waveOff[16];
    int s = v;
    #pragma unroll
    for (int off = 1; off < 64; off <<= 1) {
        int t = __shfl_up(s, off);
        if (lane >= off) s += t;
    }
    if (lane == 63) waveSums[wave] = s;
    __syncthreads();
    if (tid == 0) {
        int acc = 0;
        for (int w = 0; w < 16; w++) { waveOff[w] = acc; acc += waveSums[w]; }
        blockSums[blockIdx.x] = acc;
    }
    __syncthreads();
    if (gid < n) row_ptr[gid] = s - v + waveOff[wave];
}

__global__ void scan_sums(int* blockSums, int nb) {
    if (threadIdx.x == 0 && blockIdx.x == 0) {
        int acc = 0;
        for (int b = 0; b < nb; b++) { int t = blockSums[b]; blockSums[b] = acc; acc += t; }
    }
}

// row_ptr += blockSums[bid]; dis = rsqrt(1+count); cursor (aliases counts) = row_ptr
__global__ void finalize_scan(int* row_ptr, const int* __restrict__ blockSums,
                              int* cursor_counts, float* dis, int n) {
    int gid = blockIdx.x * 1024 + threadIdx.x;
    if (gid < n) {
        int c = cursor_counts[gid];                    // original count (pre-overwrite)
        dis[gid] = rsqrtf(1.0f + (float)c);            // self-loop folded into degree
        int rp = row_ptr[gid] + blockSums[blockIdx.x];
        row_ptr[gid] = rp;
        cursor_counts[gid] = rp;                       // becomes allocation cursor
    }
}

// norms are folded into row pre-scaling now -> CSR stores src only
__global__ void fill_csr(const int* __restrict__ src, const int* __restrict__ dst,
                         int* cursor, int* csr_src, int E) {
    int e = blockIdx.x * blockDim.x + threadIdx.x;
    if (e < E) {
        int s = src[e], d = dst[e];
        int pos = atomicAdd(&cursor[d], 1);
        csr_src[pos] = s;
    }
}

// ---------------- weight pack: fp32 [K][N] -> bf16 transposed [N][K] ----------------

__global__ void pack_w1t(const float* __restrict__ W1, short* __restrict__ W1t) {
    int i = blockIdx.x * blockDim.x + threadIdx.x;   // i = n*256 + k, n<128, k<256
    if (i < 128 * 256) {
        int n = i >> 8, k = i & 255;
        W1t[i] = f2bf(W1[k * 128 + n]);
    }
}

__global__ void pack_wcat_t(const float* __restrict__ Wmu, const float* __restrict__ Wlv,
                            short* __restrict__ Wt) {
    int i = blockIdx.x * blockDim.x + threadIdx.x;   // i = n*128 + k, n<128, k<128
    if (i < 128 * 128) {
        int n = i >> 7, k = i & 127;
        float v = (n < 64) ? Wmu[k * 64 + n] : Wlv[k * 64 + (n - 64)];
        Wt[i] = f2bf(v);
    }
}

// ---------------- MFMA GEMM: C[M,128] = A[M,K](fp32) @ W (bf16, pre-transposed Wt[128][K]) ----------------
// No LDS: N-tile = full 128 cols, so each A row is consumed by exactly one block.
// Block 256 thr = 4 waves; wave w handles rows blk*64 + w*16 .. +15, 8 col-tiles of 16x16.
// A frag (16x16x32 bf16): lane holds A[m=lane&15][k0 + (lane>>4)*8 + j], j=0..7 -> 32B fp32 load + cvt.
// B frag: lane holds W[k0+(lane>>4)*8+j][n=lane&15] = Wt[n][k0+q*8+j] -> contiguous 16B bf16 load.
// C/D:   col = lane&15, row = (lane>>4)*4 + reg  (m89-verified). Epilogue scales row by dis[row].

__launch_bounds__(256)
__global__ void gemm_mfma(const float* __restrict__ A, const short* __restrict__ Wt,
                          float* __restrict__ C, int M, int K,
                          const float* __restrict__ dis) {
    int w = threadIdx.x >> 6;
    int lane = threadIdx.x & 63;
    int ln = lane & 15;
    int q  = lane >> 4;
    int rowTile = blockIdx.x * 64 + w * 16;

    int rowA = rowTile + ln;
    if (rowA >= M) rowA = M - 1;                 // clamp; stores are guarded
    const float* aRow = A + (size_t)rowA * K + q * 8;
    const short* bBase = Wt + q * 8;

    floatx4 acc[8];
    #pragma unroll
    for (int t = 0; t < 8; t++) acc[t] = (floatx4){0.f, 0.f, 0.f, 0.f};

    for (int kt = 0; kt < K; kt += 32) {
        float4 af0 = *(const float4*)(aRow + kt);
        float4 af1 = *(const float4*)(aRow + kt + 4);
        bf16x8 aF;
        aF[0] = f2bf(af0.x); aF[1] = f2bf(af0.y); aF[2] = f2bf(af0.z); aF[3] = f2bf(af0.w);
        aF[4] = f2bf(af1.x); aF[5] = f2bf(af1.y); aF[6] = f2bf(af1.z); aF[7] = f2bf(af1.w);
        bf16x8 bF[8];
        #pragma unroll
        for (int t = 0; t < 8; t++)
            bF[t] = *(const bf16x8*)(bBase + (size_t)(t * 16 + ln) * K + kt);
        #pragma unroll
        for (int t = 0; t < 8; t++)
            acc[t] = __builtin_amdgcn_mfma_f32_16x16x32_bf16(aF, bF[t], acc[t], 0, 0, 0);
    }

    #pragma unroll
    for (int reg = 0; reg < 4; reg++) {
        int r = rowTile + q * 4 + reg;
        if (r < M) {
            float s = dis ? dis[r] : 1.f;
            #pragma unroll
            for (int t = 0; t < 8; t++)
                C[(size_t)r * 128 + t * 16 + ln] = s * acc[t][reg];
        }
    }
}

// ---------------- aggregation: one WAVE per node, float4 row gathers ----------------
// zp holds pre-scaled rows z'[i] = dis[i] * (transform(x))[i].
// out_node = dis[d] * ( sum_{s in N(d)} z'[s] + z'[d] ) + bias

#define AGG_BODY                                                            \
    int wave = threadIdx.x >> 6;                                            \
    int node = blockIdx.x * 4 + wave;                                       \
    if (node >= N) return;                                                  \
    int lane = threadIdx.x & 63;                                            \
    int half = lane >> 5;                                                   \
    int fl = lane & 31;                                                     \
    int fo = fl * 4;                                                        \
    const float* zb = zp + fo;                                              \
    int start = row_ptr[node], end = row_end[node];                         \
    float4 a0 = make_float4(0.f, 0.f, 0.f, 0.f);                            \
    float4 a1 = a0;                                                         \
    int e = start + half;                                                   \
    for (; e + 2 < end; e += 4) {                                           \
        int s0 = csr_src[e], s1 = csr_src[e + 2];                           \
        float4 z0 = *(const float4*)(zb + (size_t)s0 * 128);                \
        float4 z1 = *(const float4*)(zb + (size_t)s1 * 128);                \
        a0.x += z0.x; a0.y += z0.y; a0.z += z0.z; a0.w += z0.w;             \
        a1.x += z1.x; a1.y += z1.y; a1.z += z1.z; a1.w += z1.w;             \
    }                                                                       \
    if (e < end) {                                                          \
        int s0 = csr_src[e];                                                \
        float4 z0 = *(const float4*)(zb + (size_t)s0 * 128);                \
        a0.x += z0.x; a0.y += z0.y; a0.z += z0.z; a0.w += z0.w;             \
    }                                                                       \
    if (half == 0) {  /* self loop, added exactly once */                   \
        float4 zs = *(const float4*)(zb + (size_t)node * 128);              \
        a0.x += zs.x; a0.y += zs.y; a0.z += zs.z; a0.w += zs.w;             \
    }                                                                       \
    a0.x += a1.x; a0.y += a1.y; a0.z += a1.z; a0.w += a1.w;                 \
    a0.x += __shfl_xor(a0.x, 32);                                           \
    a0.y += __shfl_xor(a0.y, 32);                                           \
    a0.z += __shfl_xor(a0.z, 32);                                           \
    a0.w += __shfl_xor(a0.w, 32);

__launch_bounds__(256)
__global__ void agg_layer1(const float* __restrict__ zp, const int* __restrict__ row_ptr,
                           const int* __restrict__ row_end, const int* __restrict__ csr_src,
                           const float* __restrict__ dis, const float* __restrict__ b1,
                           float* __restrict__ h, int N) {
    AGG_BODY
    if (half == 0) {
        float d = dis[node];
        float4 bv = *(const float4*)(b1 + fo);
        float4 o;
        o.x = fmaf(d, a0.x, bv.x);
        o.y = fmaf(d, a0.y, bv.y);
        o.z = fmaf(d, a0.z, bv.z);
        o.w = fmaf(d, a0.w, bv.w);
        o.x = (o.x > 0.f) ? o.x : NEG_SLOPE * o.x;
        o.y = (o.y > 0.f) ? o.y : NEG_SLOPE * o.y;
        o.z = (o.z > 0.f) ? o.z : NEG_SLOPE * o.z;
        o.w = (o.w > 0.f) ? o.w : NEG_SLOPE * o.w;
        *(float4*)(h + (size_t)node * 128 + fo) = o;
    }
}

__launch_bounds__(256)
__global__ void agg_layer2(const float* __restrict__ zp, const int* __restrict__ row_ptr,
                           const int* __restrict__ row_end, const int* __restrict__ csr_src,
                           const float* __restrict__ dis, const float* __restrict__ b_mu,
                           const float* __restrict__ b_lv, float* __restrict__ out, int N) {
    AGG_BODY
    if (half == 0) {
        float d = dis[node];
        if (fl < 16) {                       // mu: features fo..fo+3
            float4 bv = *(const float4*)(b_mu + fo);
            float4 o;
            o.x = fmaf(d, a0.x, bv.x);
            o.y = fmaf(d, a0.y, bv.y);
            o.z = fmaf(d, a0.z, bv.z);
            o.w = fmaf(d, a0.w, bv.w);
            *(float4*)(out + (size_t)node * 64 + fo) = o;
        } else {                             // logvar: features fo-64..fo-61
            float4 bv = *(const float4*)(b_lv + (fo - 64));
            float4 o;
            o.x = fmaf(d, a0.x, bv.x);
            o.y = fmaf(d, a0.y, bv.y);
            o.z = fmaf(d, a0.z, bv.z);
            o.w = fmaf(d, a0.w, bv.w);
            *(float4*)(out + (size_t)N * 64 + (size_t)node * 64 + (fo - 64)) = o;
        }
    }
}

// ---------------- launcher ----------------

extern "C" void kernel_launch(void* const* d_in, const int* in_sizes, int n_in,
                              void* d_out, int out_size, void* d_ws, size_t ws_size,
                              hipStream_t stream) {
    const float* x   = (const float*)d_in[0];
    const int*   ei  = (const int*)d_in[1];    // [2,E] int32: src then dst
    const float* W1  = (const float*)d_in[2];
    const float* b1  = (const float*)d_in[3];
    const float* Wmu = (const float*)d_in[4];
    const float* bmu = (const float*)d_in[5];
    const float* Wlv = (const float*)d_in[6];
    const float* blv = (const float*)d_in[7];
    float* out = (float*)d_out;

    const int F_IN = 256;
    int N = in_sizes[0] / F_IN;   // 50000
    int E = in_sizes[1] / 2;      // 800000
    const int* e_src = ei;
    const int* e_dst = ei + E;

    char* ws = (char*)d_ws;
    size_t off = 0;
    auto carve = [&](size_t bytes) -> void* {
        void* p = ws + off;
        off += (bytes + 255) & ~(size_t)255;
        return p;
    };
    int*   counts   = (int*)  carve((size_t)N * 4);        // later: cursor / row_end
    int*   row_ptr  = (int*)  carve((size_t)N * 4);
    int*   blockSums= (int*)  carve(64 * 4);
    float* dis      = (float*)carve((size_t)N * 4);
    int*   csr_src  = (int*)  carve((size_t)E * 4);
    float* bufA     = (float*)carve((size_t)N * 128 * 4);  // Z1', then Z2'
    float* bufB     = (float*)carve((size_t)N * 128 * 4);  // h
    short* w1t      = (short*)carve(128 * 256 * 2);        // bf16 W1^T [n][k]
    short* wcatt    = (short*)carve(128 * 128 * 2);        // bf16 [Wmu|Wlv]^T [n][k]

    int nb = (N + 1023) / 1024;

    hipLaunchKernelGGL(init_counts, dim3((N + 255) / 256), dim3(256), 0, stream, counts, N);
    hipLaunchKernelGGL(count_edges, dim3((E + 255) / 256), dim3(256), 0, stream, e_dst, counts, E);
    hipLaunchKernelGGL(scan_blocks, dim3(nb), dim3(1024), 0, stream, counts, row_ptr, blockSums, N);
    hipLaunchKernelGGL(scan_sums, dim3(1), dim3(64), 0, stream, blockSums, nb);
    hipLaunchKernelGGL(finalize_scan, dim3(nb), dim3(1024), 0, stream, row_ptr, blockSums, counts, dis, N);
    hipLaunchKernelGGL(fill_csr, dim3((E + 255) / 256), dim3(256), 0, stream,
                       e_src, e_dst, counts, csr_src, E);
    hipLaunchKernelGGL(pack_w1t, dim3(128), dim3(256), 0, stream, W1, w1t);
    hipLaunchKernelGGL(pack_wcat_t, dim3(64), dim3(256), 0, stream, Wmu, Wlv, wcatt);
    // layer 1: Z1' = dis .* (x @ W1) ; h = leaky(dis .* Agg(Z1') + b1)
    hipLaunchKernelGGL(gemm_mfma, dim3((N + 63) / 64), dim3(256), 0, stream, x, w1t, bufA, N, 256, dis);
    hipLaunchKernelGGL(agg_layer1, dim3((N + 3) / 4), dim3(256), 0, stream,
                       bufA, row_ptr, counts, csr_src, dis, b1, bufB, N);
    // layer 2 (mu & logvar share the aggregation): Z2' = dis .* (h @ [Wmu|Wlv])
    hipLaunchKernelGGL(gemm_mfma, dim3((N + 63) / 64), dim3(256), 0, stream, bufB, wcatt, bufA, N, 128, dis);
    hipLaunchKernelGGL(agg_layer2, dim3((N + 3) / 4), dim3(256), 0, stream,
                       bufA, row_ptr, counts, csr_src, dis, bmu, blv, out, N);
}

// Round 4
// 332.552 us; speedup vs baseline: 1.4087x; 1.1204x over previous
//
#include <hip/hip_runtime.h>

#define NEG_SLOPE 0.01f

typedef __attribute__((ext_vector_type(8))) short bf16x8;
typedef __attribute__((ext_vector_type(4))) float floatx4;

__device__ __forceinline__ short f2bf(float f) {
    union { float f; unsigned u; } v; v.f = f;
    unsigned u = v.u;
    u += 0x7FFF + ((u >> 16) & 1);          // round-to-nearest-even
    return (short)(u >> 16);
}
__device__ __forceinline__ float bf2f(short s) {
    union { unsigned u; float f; } v;
    v.u = ((unsigned)(unsigned short)s) << 16;
    return v.f;
}

// ---------------- degree / CSR build ----------------

__global__ void init_counts(int* counts, int n) {
    int i = blockIdx.x * blockDim.x + threadIdx.x;
    if (i < n) counts[i] = 0;
}

__global__ void count_edges(const int* __restrict__ dst, int* counts, int E) {
    int e = blockIdx.x * blockDim.x + threadIdx.x;
    if (e < E) atomicAdd(&counts[dst[e]], 1);
}

// per-1024-block exclusive scan; blockSums[b] = block total
__global__ void scan_blocks(const int* __restrict__ counts, int* row_ptr,
                            int* blockSums, int n) {
    int tid = threadIdx.x;
    int gid = blockIdx.x * 1024 + tid;
    int v = (gid < n) ? counts[gid] : 0;
    int lane = tid & 63, wave = tid >> 6;
    __shared__ int waveSums[16];
    __shared__ int waveOff[16];
    int s = v;
    #pragma unroll
    for (int off = 1; off < 64; off <<= 1) {
        int t = __shfl_up(s, off);
        if (lane >= off) s += t;
    }
    if (lane == 63) waveSums[wave] = s;
    __syncthreads();
    if (tid == 0) {
        int acc = 0;
        for (int w = 0; w < 16; w++) { waveOff[w] = acc; acc += waveSums[w]; }
        blockSums[blockIdx.x] = acc;
    }
    __syncthreads();
    if (gid < n) row_ptr[gid] = s - v + waveOff[wave];
}

__global__ void scan_sums(int* blockSums, int nb) {
    if (threadIdx.x == 0 && blockIdx.x == 0) {
        int acc = 0;
        for (int b = 0; b < nb; b++) { int t = blockSums[b]; blockSums[b] = acc; acc += t; }
    }
}

// row_ptr += blockSums[bid]; dis = rsqrt(1+count); cursor (aliases counts) = row_ptr
__global__ void finalize_scan(int* row_ptr, const int* __restrict__ blockSums,
                              int* cursor_counts, float* dis, int n) {
    int gid = blockIdx.x * 1024 + threadIdx.x;
    if (gid < n) {
        int c = cursor_counts[gid];                    // original count (pre-overwrite)
        dis[gid] = rsqrtf(1.0f + (float)c);            // self-loop folded into degree
        int rp = row_ptr[gid] + blockSums[blockIdx.x];
        row_ptr[gid] = rp;
        cursor_counts[gid] = rp;                       // becomes allocation cursor
    }
}

// norms are folded into row pre-scaling now -> CSR stores src only
__global__ void fill_csr(const int* __restrict__ src, const int* __restrict__ dst,
                         int* cursor, int* csr_src, int E) {
    int e = blockIdx.x * blockDim.x + threadIdx.x;
    if (e < E) {
        int s = src[e], d = dst[e];
        int pos = atomicAdd(&cursor[d], 1);
        csr_src[pos] = s;
    }
}

// ---------------- weight pack: fp32 [K][N] -> bf16 transposed [N][K] ----------------

__global__ void pack_w1t(const float* __restrict__ W1, short* __restrict__ W1t) {
    int i = blockIdx.x * blockDim.x + threadIdx.x;   // i = n*256 + k, n<128, k<256
    if (i < 128 * 256) {
        int n = i >> 8, k = i & 255;
        W1t[i] = f2bf(W1[k * 128 + n]);
    }
}

__global__ void pack_wcat_t(const float* __restrict__ Wmu, const float* __restrict__ Wlv,
                            short* __restrict__ Wt) {
    int i = blockIdx.x * blockDim.x + threadIdx.x;   // i = n*128 + k, n<128, k<128
    if (i < 128 * 128) {
        int n = i >> 7, k = i & 127;
        float v = (n < 64) ? Wmu[k * 64 + n] : Wlv[k * 64 + (n - 64)];
        Wt[i] = f2bf(v);
    }
}

// ---------------- MFMA GEMM: C[M,128](bf16) = A[M,K] @ W (bf16 Wt[128][K]) ----------------
// No LDS: N-tile = full 128 cols. Block 256 thr = 4 waves; wave w: rows blk*64+w*16..+15.
// A frag (16x16x32): lane holds A[m=lane&15][k0+(lane>>4)*8+j]; fp32 A converts, bf16 A loads direct.
// B frag: lane holds Wt[n=lane&15 + t*16][k0+q*8+j] -> contiguous 16B bf16 load.
// C/D: col=lane&15, row=(lane>>4)*4+reg (m89-verified). Epilogue: row scale by dis[row], cvt bf16.

template<bool ABF16>
__launch_bounds__(256)
__global__ void gemm_mfma(const void* __restrict__ Ap, const short* __restrict__ Wt,
                          short* __restrict__ C, int M, int K,
                          const float* __restrict__ dis) {
    int w = threadIdx.x >> 6;
    int lane = threadIdx.x & 63;
    int ln = lane & 15;
    int q  = lane >> 4;
    int rowTile = blockIdx.x * 64 + w * 16;

    int rowA = rowTile + ln;
    if (rowA >= M) rowA = M - 1;                 // clamp; stores are guarded
    const short* bBase = Wt + q * 8;

    floatx4 acc[8];
    #pragma unroll
    for (int t = 0; t < 8; t++) acc[t] = (floatx4){0.f, 0.f, 0.f, 0.f};

    const float* aRowF = (const float*)Ap + (size_t)rowA * K + q * 8;
    const short* aRowB = (const short*)Ap + (size_t)rowA * K + q * 8;

    for (int kt = 0; kt < K; kt += 32) {
        bf16x8 aF;
        if (ABF16) {
            aF = *(const bf16x8*)(aRowB + kt);
        } else {
            float4 af0 = *(const float4*)(aRowF + kt);
            float4 af1 = *(const float4*)(aRowF + kt + 4);
            aF[0] = f2bf(af0.x); aF[1] = f2bf(af0.y); aF[2] = f2bf(af0.z); aF[3] = f2bf(af0.w);
            aF[4] = f2bf(af1.x); aF[5] = f2bf(af1.y); aF[6] = f2bf(af1.z); aF[7] = f2bf(af1.w);
        }
        bf16x8 bF[8];
        #pragma unroll
        for (int t = 0; t < 8; t++)
            bF[t] = *(const bf16x8*)(bBase + (size_t)(t * 16 + ln) * K + kt);
        #pragma unroll
        for (int t = 0; t < 8; t++)
            acc[t] = __builtin_amdgcn_mfma_f32_16x16x32_bf16(aF, bF[t], acc[t], 0, 0, 0);
    }

    #pragma unroll
    for (int reg = 0; reg < 4; reg++) {
        int r = rowTile + q * 4 + reg;
        if (r < M) {
            float s = dis ? dis[r] : 1.f;
            #pragma unroll
            for (int t = 0; t < 8; t++)
                C[(size_t)r * 128 + t * 16 + ln] = f2bf(s * acc[t][reg]);
        }
    }
}

// ---------------- aggregation: one WAVE per node, bf16 rows, quarter-wave gathers ----------------
// zp holds pre-scaled bf16 rows z'[i] = dis[i] * (transform(x))[i]  (128 feats = 256B).
// out_node = dis[d] * ( sum_{s in N(d)} z'[s] + z'[d] ) + bias
// Quarter-wave qi (16 lanes x 16B bf16x8) gathers a full row per instruction;
// qi handles CSR slots e == start+qi (mod 4); unroll x2 -> 8 gathers in flight/wave.

#define AGG_BODY_BF16                                                         \
    int wave = threadIdx.x >> 6;                                              \
    int node = blockIdx.x * 4 + wave;                                         \
    if (node >= N) return;                                                    \
    int lane = threadIdx.x & 63;                                              \
    int qi = lane >> 4;                                                       \
    int fl = lane & 15;                                                       \
    int fo = fl * 8;                                                          \
    const short* zb = zp + fo;                                                \
    int start = row_ptr[node], end = row_end[node];                           \
    float acc[8];                                                             \
    _Pragma("unroll")                                                         \
    for (int j = 0; j < 8; j++) acc[j] = 0.f;                                 \
    int e = start + qi;                                                       \
    for (; e + 4 < end; e += 8) {                                             \
        int s0 = csr_src[e], s1 = csr_src[e + 4];                             \
        bf16x8 z0 = *(const bf16x8*)(zb + (size_t)s0 * 128);                  \
        bf16x8 z1 = *(const bf16x8*)(zb + (size_t)s1 * 128);                  \
        _Pragma("unroll")                                                     \
        for (int j = 0; j < 8; j++) acc[j] += bf2f(z0[j]) + bf2f(z1[j]);      \
    }                                                                         \
    for (; e < end; e += 4) {                                                 \
        int s0 = csr_src[e];                                                  \
        bf16x8 z0 = *(const bf16x8*)(zb + (size_t)s0 * 128);                  \
        _Pragma("unroll")                                                     \
        for (int j = 0; j < 8; j++) acc[j] += bf2f(z0[j]);                    \
    }                                                                         \
    if (qi == 0) {  /* self loop, added exactly once */                       \
        bf16x8 zs = *(const bf16x8*)(zb + (size_t)node * 128);                \
        _Pragma("unroll")                                                     \
        for (int j = 0; j < 8; j++) acc[j] += bf2f(zs[j]);                    \
    }                                                                         \
    _Pragma("unroll")                                                         \
    for (int j = 0; j < 8; j++) {                                             \
        acc[j] += __shfl_xor(acc[j], 16);                                     \
        acc[j] += __shfl_xor(acc[j], 32);                                     \
    }

__launch_bounds__(256)
__global__ void agg_layer1(const short* __restrict__ zp, const int* __restrict__ row_ptr,
                           const int* __restrict__ row_end, const int* __restrict__ csr_src,
                           const float* __restrict__ dis, const float* __restrict__ b1,
                           short* __restrict__ h, int N) {
    AGG_BODY_BF16
    if (qi == 0) {
        float d = dis[node];
        bf16x8 ov;
        #pragma unroll
        for (int j = 0; j < 8; j++) {
            float v = fmaf(d, acc[j], b1[fo + j]);
            v = (v > 0.f) ? v : NEG_SLOPE * v;
            ov[j] = f2bf(v);
        }
        *(bf16x8*)(h + (size_t)node * 128 + fo) = ov;
    }
}

__launch_bounds__(256)
__global__ void agg_layer2(const short* __restrict__ zp, const int* __restrict__ row_ptr,
                           const int* __restrict__ row_end, const int* __restrict__ csr_src,
                           const float* __restrict__ dis, const float* __restrict__ b_mu,
                           const float* __restrict__ b_lv, float* __restrict__ out, int N) {
    AGG_BODY_BF16
    if (qi == 0) {
        float d = dis[node];
        float r[8];
        if (fl < 8) {                        // mu: features fo..fo+7
            #pragma unroll
            for (int j = 0; j < 8; j++) r[j] = fmaf(d, acc[j], b_mu[fo + j]);
            float* p = out + (size_t)node * 64 + fo;
            *(float4*)p       = make_float4(r[0], r[1], r[2], r[3]);
            *(float4*)(p + 4) = make_float4(r[4], r[5], r[6], r[7]);
        } else {                             // logvar: features fo-64..fo-57
            #pragma unroll
            for (int j = 0; j < 8; j++) r[j] = fmaf(d, acc[j], b_lv[fo - 64 + j]);
            float* p = out + (size_t)N * 64 + (size_t)node * 64 + (fo - 64);
            *(float4*)p       = make_float4(r[0], r[1], r[2], r[3]);
            *(float4*)(p + 4) = make_float4(r[4], r[5], r[6], r[7]);
        }
    }
}

// ---------------- launcher ----------------

extern "C" void kernel_launch(void* const* d_in, const int* in_sizes, int n_in,
                              void* d_out, int out_size, void* d_ws, size_t ws_size,
                              hipStream_t stream) {
    const float* x   = (const float*)d_in[0];
    const int*   ei  = (const int*)d_in[1];    // [2,E] int32: src then dst
    const float* W1  = (const float*)d_in[2];
    const float* b1  = (const float*)d_in[3];
    const float* Wmu = (const float*)d_in[4];
    const float* bmu = (const float*)d_in[5];
    const float* Wlv = (const float*)d_in[6];
    const float* blv = (const float*)d_in[7];
    float* out = (float*)d_out;

    const int F_IN = 256;
    int N = in_sizes[0] / F_IN;   // 50000
    int E = in_sizes[1] / 2;      // 800000
    const int* e_src = ei;
    const int* e_dst = ei + E;

    char* ws = (char*)d_ws;
    size_t off = 0;
    auto carve = [&](size_t bytes) -> void* {
        void* p = ws + off;
        off += (bytes + 255) & ~(size_t)255;
        return p;
    };
    int*   counts   = (int*)  carve((size_t)N * 4);        // later: cursor / row_end
    int*   row_ptr  = (int*)  carve((size_t)N * 4);
    int*   blockSums= (int*)  carve(64 * 4);
    float* dis      = (float*)carve((size_t)N * 4);
    int*   csr_src  = (int*)  carve((size_t)E * 4);
    short* bufA     = (short*)carve((size_t)N * 128 * 2);  // bf16 Z1', then Z2'
    short* bufB     = (short*)carve((size_t)N * 128 * 2);  // bf16 h
    short* w1t      = (short*)carve(128 * 256 * 2);        // bf16 W1^T [n][k]
    short* wcatt    = (short*)carve(128 * 128 * 2);        // bf16 [Wmu|Wlv]^T [n][k]

    int nb = (N + 1023) / 1024;

    hipLaunchKernelGGL(init_counts, dim3((N + 255) / 256), dim3(256), 0, stream, counts, N);
    hipLaunchKernelGGL(count_edges, dim3((E + 255) / 256), dim3(256), 0, stream, e_dst, counts, E);
    hipLaunchKernelGGL(scan_blocks, dim3(nb), dim3(1024), 0, stream, counts, row_ptr, blockSums, N);
    hipLaunchKernelGGL(scan_sums, dim3(1), dim3(64), 0, stream, blockSums, nb);
    hipLaunchKernelGGL(finalize_scan, dim3(nb), dim3(1024), 0, stream, row_ptr, blockSums, counts, dis, N);
    hipLaunchKernelGGL(fill_csr, dim3((E + 255) / 256), dim3(256), 0, stream,
                       e_src, e_dst, counts, csr_src, E);
    hipLaunchKernelGGL(pack_w1t, dim3(128), dim3(256), 0, stream, W1, w1t);
    hipLaunchKernelGGL(pack_wcat_t, dim3(64), dim3(256), 0, stream, Wmu, Wlv, wcatt);
    // layer 1: Z1' = dis .* (x @ W1) ; h = leaky(dis .* Agg(Z1') + b1)
    hipLaunchKernelGGL((gemm_mfma<false>), dim3((N + 63) / 64), dim3(256), 0, stream,
                       (const void*)x, w1t, bufA, N, 256, dis);
    hipLaunchKernelGGL(agg_layer1, dim3((N + 3) / 4), dim3(256), 0, stream,
                       bufA, row_ptr, counts, csr_src, dis, b1, bufB, N);
    // layer 2 (mu & logvar share the aggregation): Z2' = dis .* (h @ [Wmu|Wlv])
    hipLaunchKernelGGL((gemm_mfma<true>), dim3((N + 63) / 64), dim3(256), 0, stream,
                       (const void*)bufB, wcatt, bufA, N, 128, dis);
    hipLaunchKernelGGL(agg_layer2, dim3((N + 3) / 4), dim3(256), 0, stream,
                       bufA, row_ptr, counts, csr_src, dis, bmu, blv, out, N);
}